// Round 1
// baseline (258.287 us; speedup 1.0000x reference)
//
#include <hip/hip_runtime.h>
#include <hip/hip_bf16.h>

// Problem constants (from reference): B=2, S=2048, D=1024, H=16, DK=64
#define B_  2
#define S_  2048
#define D_  1024
#define H_  16
#define DK_ 64

using bf16 = __hip_bfloat16;
typedef __bf16 bf16x8 __attribute__((ext_vector_type(8)));
typedef float  f32x4  __attribute__((ext_vector_type(4)));

__device__ inline void st1(float* p, float v) { *p = v; }
__device__ inline void st1(bf16*  p, float v) { *p = __float2bfloat16(v); }

// Async global->LDS, 16B per lane. LDS dest = wave-uniform base + lane*16.
__device__ inline void gll16(const bf16* g, bf16* l) {
    __builtin_amdgcn_global_load_lds(
        (const __attribute__((address_space(1))) unsigned int*)g,
        (__attribute__((address_space(3))) unsigned int*)l, 16, 0, 0);
}

// ---------------------------------------------------------------------------
// f32 -> bf16 conversion: 7 regions (q,k,v = nbig; Wq,Wk,Wv,Wo = nsmall).
// ---------------------------------------------------------------------------
__global__ __launch_bounds__(256) void cvt_kernel(
    const float* __restrict__ s0, const float* __restrict__ s1,
    const float* __restrict__ s2, const float* __restrict__ s3,
    const float* __restrict__ s4, const float* __restrict__ s5,
    const float* __restrict__ s6,
    bf16* __restrict__ d0, bf16* __restrict__ d1, bf16* __restrict__ d2,
    bf16* __restrict__ d3, bf16* __restrict__ d4, bf16* __restrict__ d5,
    bf16* __restrict__ d6, int nbig, int nsmall)
{
    const int z = blockIdx.y;
    const float* s; bf16* d; int n;
    switch (z) {
        case 0: s = s0; d = d0; n = nbig;   break;
        case 1: s = s1; d = d1; n = nbig;   break;
        case 2: s = s2; d = d2; n = nbig;   break;
        case 3: s = s3; d = d3; n = nsmall; break;
        case 4: s = s4; d = d4; n = nsmall; break;
        case 5: s = s5; d = d5; n = nsmall; break;
        default: s = s6; d = d6; n = nsmall; break;
    }
    const int idx = (blockIdx.x * 256 + threadIdx.x) * 4;
    if (idx < n) {
        const float4 v = *reinterpret_cast<const float4*>(s + idx);
        union { ushort4 u; __bf16 h[4]; } r;
        r.h[0] = (__bf16)v.x; r.h[1] = (__bf16)v.y;
        r.h[2] = (__bf16)v.z; r.h[3] = (__bf16)v.w;
        *reinterpret_cast<ushort4*>(d + idx) = r.u;
    }
}

// ---------------------------------------------------------------------------
// GEMM: C[M,N] = A[M,K] @ W[N,K]^T + bias[N]; A,W bf16; bias f32; C per TC.
// m97 structure: BMx128 tile, BK=32, global_load_lds width-16 staging,
// 4 waves 2x2. BM=128: wave 64x64 via 4x4 of 16x16x32 (proven ~900 TF).
// BM=64: wave 32x64 via 2x4 -> twice the blocks, for grids that would
// otherwise be 1 block/CU (out-projection: 256 -> 512 blocks).
// ---------------------------------------------------------------------------
template <typename TC, bool VT3, int BM>
__global__ __launch_bounds__(256, BM == 128 ? 3 : 4) void gemm_bt_kernel(
    const bf16* __restrict__ A0, const bf16* __restrict__ A1, const bf16* __restrict__ A2,
    const bf16* __restrict__ W0, const bf16* __restrict__ W1, const bf16* __restrict__ W2,
    const float* __restrict__ b0, const float* __restrict__ b1, const float* __restrict__ b2,
    TC* __restrict__ C0, TC* __restrict__ C1, TC* __restrict__ C2,
    int M, int N, int K)
{
    const int z = blockIdx.z;
    const bf16*  A    = (z == 0) ? A0 : (z == 1) ? A1 : A2;
    const bf16*  W    = (z == 0) ? W0 : (z == 1) ? W1 : W2;
    const float* bias = (z == 0) ? b0 : (z == 1) ? b1 : b2;
    TC*          C    = (z == 0) ? C0 : (z == 1) ? C1 : C2;

    __shared__ bf16 As[BM][32];    // 64 B rows, NO pad (async-copy layout)
    __shared__ bf16 Bs[128][32];

    const int t    = threadIdx.x;
    const int lane = t & 63;
    const int wave = t >> 6;
    const int quad = lane >> 4;
    const int l16  = lane & 15;
    const int wm   = wave >> 1;
    const int wn   = wave & 1;

    const int m0 = blockIdx.y * BM;
    const int n0 = blockIdx.x * 128;

    constexpr int RPW = BM / 4;          // A rows staged per wave
    constexpr int MI  = BM / 32;         // 16-row fragments per wave in M
    const int ar0 = wave * RPW + (lane >> 2);
    const int br0 = wave * 32  + (lane >> 2);
    const int c0  = (lane & 3) * 8;
    const bf16* Ab = A + (size_t)(m0 + ar0) * K + c0;
    const bf16* Bb = W + (size_t)(n0 + br0) * K + c0;
    bf16* asd = &As[wave * RPW][0];
    bf16* bsd = &Bs[wave * 32][0];

    f32x4 acc[MI][4] = {};

    for (int kt = 0; kt < K; kt += 32) {
        __syncthreads();
        gll16(Ab + kt, asd);
        if constexpr (BM == 128) gll16(Ab + 16 * K + kt, asd + 16 * 32);
        gll16(Bb + kt, bsd);
        gll16(Bb + 16 * K + kt, bsd + 16 * 32);
        __syncthreads();

        bf16x8 af[MI], bfr[4];
#pragma unroll
        for (int mi = 0; mi < MI; mi++)
            af[mi] = *reinterpret_cast<const bf16x8*>(&As[wm * (BM / 2) + mi * 16 + l16][quad * 8]);
#pragma unroll
        for (int ni = 0; ni < 4; ni++)
            bfr[ni] = *reinterpret_cast<const bf16x8*>(&Bs[wn * 64 + ni * 16 + l16][quad * 8]);
#pragma unroll
        for (int mi = 0; mi < MI; mi++)
#pragma unroll
            for (int ni = 0; ni < 4; ni++)
                acc[mi][ni] = __builtin_amdgcn_mfma_f32_16x16x32_bf16(
                    af[mi], bfr[ni], acc[mi][ni], 0, 0, 0);
    }

    if (VT3 && z == 2) {
#pragma unroll
        for (int ni = 0; ni < 4; ni++) {
            const int col = n0 + wn * 64 + ni * 16 + l16;
            const float bvv = bias[col];
            const int hh = col >> 6, dh = col & 63;
#pragma unroll
            for (int mi = 0; mi < MI; mi++) {
                const int rb  = m0 + wm * (BM / 2) + mi * 16 + quad * 4;
                const int bb  = rb >> 11;
                const int tok = rb & (S_ - 1);
                union { ushort4 u; __bf16 h[4]; } pk;
#pragma unroll
                for (int i = 0; i < 4; i++)
                    pk.h[i] = (__bf16)(acc[mi][ni][i] + bvv);
                bf16* vt = (bf16*)C + ((size_t)(bb * H_ + hh) * DK_ + dh) * S_ + tok;
                *reinterpret_cast<ushort4*>(vt) = pk.u;
            }
        }
    } else {
#pragma unroll
        for (int ni = 0; ni < 4; ni++) {
            const int col = n0 + wn * 64 + ni * 16 + l16;
            const float bvv = bias[col];
#pragma unroll
            for (int mi = 0; mi < MI; mi++) {
#pragma unroll
                for (int i = 0; i < 4; i++) {
                    const int row = m0 + wm * (BM / 2) + mi * 16 + quad * 4 + i;
                    st1(&C[(size_t)row * N + col], acc[mi][ni][i] + bvv);
                }
            }
        }
    }
}

// ---------------------------------------------------------------------------
// Flash attention (causal), no-max exp2 softmax (validated R5-R7).
// K and V^T chunks staged into LDS via global_load_lds DMA, double-buffered:
// chunk it+1's DMA issues AFTER the barrier and drains at the NEXT barrier
// -> in flight across all of chunk it's compute.
// This round: UNPAIRED tiles. One 64-row q-tile per block, grid.x = 32
// (1024 blocks total -> 4 blocks/CU avg, 3 resident vs previous 2).
// til = 31 - blockIdx.x so the 32-chunk blocks dispatch first and the
// 1-chunk blocks drain the scheduler tail. Wave w owns rows
// [til*64+16w, +16): no split-K, no combine. Only the diagonal chunk
// (it == til) masks. XOR swizzle breaks the 128B-row-stride bank pathology.
// AO aliases Qp: tile's Q rows are read only by its own block, before the
// epilogue write; tiles are disjoint across blocks. Race-free.
// ---------------------------------------------------------------------------
__global__ __launch_bounds__(256, 3) void attn_kernel(
    const bf16* __restrict__ Qp, const bf16* __restrict__ Kp,
    const bf16* __restrict__ VT, bf16* __restrict__ AO)
{
    const int t    = threadIdx.x;
    const int lane = t & 63;
    const int wave = t >> 6;
    const int quad = lane >> 4;
    const int l16  = lane & 15;

    const int til = 31 - blockIdx.x;      // long tiles dispatch first
    const int h = blockIdx.y;
    const int b = blockIdx.z;
    const size_t bh = (size_t)b * S_ * D_ + (size_t)h * DK_;
    const bf16* vtb = VT + (size_t)(b * H_ + h) * DK_ * S_;

    __shared__ bf16 Ks[2][64][64];     // [buf][key][dk]   8 KB per buf
    __shared__ bf16 Vs[2][64][64];     // [buf][dh][key]   8 KB per buf
    __shared__ bf16 Pb[4][16][72];     // per-wave P tile (144 B rows)

    // staging lane constants: lane -> (row-within-8, swizzled col-group)
    const int sR = lane >> 3;                 // 0..7
    const int scg = ((lane & 7) ^ sR) * 8;    // element offset, XOR swizzle
    const int swz0 = (quad ^ (l16 & 7)) * 8;        // read swizzle, cols 0..31
    const int swz1 = ((quad + 4) ^ (l16 & 7)) * 8;  // read swizzle, cols 32..63

    const float QSC = 0.18033688f;   // 0.125 * log2(e)
    const float NEG = -1e30f;

    bf16x8 onesf;
#pragma unroll
    for (int j = 0; j < 8; j++) onesf[j] = (__bf16)1.0f;

    // Q fragments for this wave's 16 rows of the tile
    bf16x8 qf0, qf1;
    {
        const bf16* qrow = Qp + bh + (size_t)(til * 64 + wave * 16 + l16) * D_;
        qf0 = *reinterpret_cast<const bf16x8*>(qrow + quad * 8);
        qf1 = *reinterpret_cast<const bf16x8*>(qrow + 32 + quad * 8);
#pragma unroll
        for (int j = 0; j < 8; j++) {
            qf0[j] = (__bf16)((float)qf0[j] * QSC);
            qf1[j] = (__bf16)((float)qf1[j] * QSC);
        }
    }

    f32x4 lacc = {};
    f32x4 oacc[4] = {};

    const int ntot = til + 1;         // causal: chunks 0..til

    // stage chunk 0 (keys 0..63) into buffer 0
    {
#pragma unroll
        for (int j = 0; j < 2; j++) {
            const int R = wave * 16 + j * 8 + sR;
            gll16(Kp + bh + (size_t)R * D_ + scg, &Ks[0][wave * 16 + j * 8][0]);
            gll16(vtb + (size_t)R * S_ + scg,     &Vs[0][wave * 16 + j * 8][0]);
        }
    }

    for (int it = 0; it < ntot; it++) {
        __syncthreads();   // drains DMA for chunk `it`; prev-buf reads done

        // issue DMA for chunk it+1 (drains at NEXT barrier -> true async)
        if (it + 1 < ntot) {
            const int k0n = (it + 1) * 64;
            const int bufn = (it + 1) & 1;
#pragma unroll
            for (int j = 0; j < 2; j++) {
                const int R = wave * 16 + j * 8 + sR;
                gll16(Kp + bh + (size_t)(k0n + R) * D_ + scg, &Ks[bufn][wave * 16 + j * 8][0]);
                gll16(vtb + (size_t)R * S_ + k0n + scg,       &Vs[bufn][wave * 16 + j * 8][0]);
            }
        }

        const int k0  = it * 64;
        const int buf = it & 1;
        const int qw0 = til * 64 + wave * 16;

        // QK^T from staged K (swizzled b128 reads)
        f32x4 sc[4];
#pragma unroll
        for (int ch = 0; ch < 4; ch++) {
            const int row = ch * 16 + l16;
            bf16x8 kfa = *reinterpret_cast<const bf16x8*>(&Ks[buf][row][swz0]);
            bf16x8 kfb = *reinterpret_cast<const bf16x8*>(&Ks[buf][row][swz1]);
            f32x4 zz = {};
            zz = __builtin_amdgcn_mfma_f32_16x16x32_bf16(qf0, kfa, zz, 0, 0, 0);
            sc[ch] = __builtin_amdgcn_mfma_f32_16x16x32_bf16(qf1, kfb, zz, 0, 0, 0);
        }

        // exp2 softmax (no max-sub); mask only the diagonal chunk
        const bool bnd = (it == til);
#pragma unroll
        for (int i = 0; i < 4; i++) {
            const int r = quad * 4 + i;
            float s0 = sc[0][i], s1 = sc[1][i], s2 = sc[2][i], s3 = sc[3][i];
            if (bnd) {
                const int qi = qw0 + r;
                s0 = (k0 + l16      <= qi) ? s0 : NEG;
                s1 = (k0 + 16 + l16 <= qi) ? s1 : NEG;
                s2 = (k0 + 32 + l16 <= qi) ? s2 : NEG;
                s3 = (k0 + 48 + l16 <= qi) ? s3 : NEG;
            }
            Pb[wave][r][l16]      = __float2bfloat16(__builtin_amdgcn_exp2f(s0));
            Pb[wave][r][16 + l16] = __float2bfloat16(__builtin_amdgcn_exp2f(s1));
            Pb[wave][r][32 + l16] = __float2bfloat16(__builtin_amdgcn_exp2f(s2));
            Pb[wave][r][48 + l16] = __float2bfloat16(__builtin_amdgcn_exp2f(s3));
        }
        // wave-private LDS round-trip: drain ds_writes before reads
        asm volatile("s_waitcnt lgkmcnt(0)" ::: "memory");
        bf16x8 pf0 = *reinterpret_cast<const bf16x8*>(&Pb[wave][l16][quad * 8]);
        bf16x8 pf1 = *reinterpret_cast<const bf16x8*>(&Pb[wave][l16][32 + quad * 8]);

        lacc = __builtin_amdgcn_mfma_f32_16x16x32_bf16(pf0, onesf, lacc, 0, 0, 0);
        lacc = __builtin_amdgcn_mfma_f32_16x16x32_bf16(pf1, onesf, lacc, 0, 0, 0);

        // PV from staged V^T (swizzled b128 reads)
#pragma unroll
        for (int n = 0; n < 4; n++) {
            const int row = n * 16 + l16;
            bf16x8 vt0 = *reinterpret_cast<const bf16x8*>(&Vs[buf][row][swz0]);
            bf16x8 vt1 = *reinterpret_cast<const bf16x8*>(&Vs[buf][row][swz1]);
            oacc[n] = __builtin_amdgcn_mfma_f32_16x16x32_bf16(pf0, vt0, oacc[n], 0, 0, 0);
            oacc[n] = __builtin_amdgcn_mfma_f32_16x16x32_bf16(pf1, vt1, oacc[n], 0, 0, 0);
        }
    }

    // epilogue
    {
        const int qw0 = til * 64 + wave * 16;
#pragma unroll
        for (int i = 0; i < 4; i++) {
            const float inv = 1.0f / lacc[i];
#pragma unroll
            for (int n = 0; n < 4; n++)
                AO[bh + (size_t)(qw0 + quad * 4 + i) * D_ + n * 16 + l16] =
                    __float2bfloat16(oacc[n][i] * inv);
        }
    }
}

// ---------------------------------------------------------------------------
extern "C" void kernel_launch(void* const* d_in, const int* in_sizes, int n_in,
                              void* d_out, int out_size, void* d_ws, size_t ws_size,
                              hipStream_t stream)
{
    const float* q  = (const float*)d_in[0];
    const float* k  = (const float*)d_in[1];
    const float* v  = (const float*)d_in[2];
    // d_in[3]: causal mask (int32 tril) — applied analytically
    const float* Wq = (const float*)d_in[4];
    const float* bq = (const float*)d_in[5];
    const float* Wk = (const float*)d_in[6];
    const float* bk = (const float*)d_in[7];
    const float* Wv = (const float*)d_in[8];
    const float* bv = (const float*)d_in[9];
    const float* Wo = (const float*)d_in[10];
    const float* bo = (const float*)d_in[11];
    float* out = (float*)d_out;

    bf16* ws = (bf16*)d_ws;
    const size_t MD = (size_t)(B_ * S_) * D_;   // 4,194,304
    const size_t WN = (size_t)D_ * D_;          // 1,048,576
    bf16* qb  = ws;
    bf16* kb  = ws + MD;
    bf16* vb  = ws + 2 * MD;
    bf16* wqb = ws + 3 * MD;
    bf16* wkb = wqb + WN;
    bf16* wvb = wkb + WN;
    bf16* wob = wvb + WN;
    bf16* Qp  = wob + WN;
    bf16* Kp  = Qp + MD;
    bf16* VT  = Kp + MD;    // total 6*MD + 4*WN ~= 58.7 MB
    bf16* AO  = Qp;         // alias: safe (see attn_kernel note)

    const int M = B_ * S_;  // 4096

    // 1) convert all f32 operands to bf16 (one launch, 7 regions)
    cvt_kernel<<<dim3((int)(MD / 4 / 256), 7), 256, 0, stream>>>(
        q, k, v, Wq, Wk, Wv, Wo, qb, kb, vb, wqb, wkb, wvb, wob,
        (int)MD, (int)WN);

    // 2) QKV projections (z batched); z==2 writes V^T per head
    gemm_bt_kernel<bf16, true, 128><<<dim3(D_ / 128, M / 128, 3), 256, 0, stream>>>(
        qb, kb, vb, wqb, wkb, wvb, bq, bk, bv, Qp, Kp, VT, M, D_, D_);

    // 3) causal flash attention (DMA-staged K/V, one tile per block)
    attn_kernel<<<dim3(32, H_, B_), 256, 0, stream>>>(Qp, Kp, VT, AO);

    // 4) output projection -> f32 out (BM=64: 512 blocks vs 256)
    gemm_bt_kernel<float, false, 64><<<dim3(D_ / 128, M / 64, 1), 256, 0, stream>>>(
        AO, AO, AO, wob, wob, wob, bo, bo, bo, out, out, out, M, D_, D_);
}

// Round 2
// 237.580 us; speedup vs baseline: 1.0872x; 1.0872x over previous
//
#include <hip/hip_runtime.h>
#include <hip/hip_bf16.h>

// Problem constants (from reference): B=2, S=2048, D=1024, H=16, DK=64
#define B_  2
#define S_  2048
#define D_  1024
#define H_  16
#define DK_ 64

using bf16 = __hip_bfloat16;
typedef __bf16 bf16x8 __attribute__((ext_vector_type(8)));
typedef float  f32x4  __attribute__((ext_vector_type(4)));

__device__ inline void st1(float* p, float v) { *p = v; }
__device__ inline void st1(bf16*  p, float v) { *p = __float2bfloat16(v); }

// Async global->LDS, 16B per lane. LDS dest = wave-uniform base + lane*16.
__device__ inline void gll16(const bf16* g, bf16* l) {
    __builtin_amdgcn_global_load_lds(
        (const __attribute__((address_space(1))) unsigned int*)g,
        (__attribute__((address_space(3))) unsigned int*)l, 16, 0, 0);
}

// ---------------------------------------------------------------------------
// f32 -> bf16 conversion: 7 regions (q,k,v = nbig; Wq,Wk,Wv,Wo = nsmall).
// ---------------------------------------------------------------------------
__global__ __launch_bounds__(256) void cvt_kernel(
    const float* __restrict__ s0, const float* __restrict__ s1,
    const float* __restrict__ s2, const float* __restrict__ s3,
    const float* __restrict__ s4, const float* __restrict__ s5,
    const float* __restrict__ s6,
    bf16* __restrict__ d0, bf16* __restrict__ d1, bf16* __restrict__ d2,
    bf16* __restrict__ d3, bf16* __restrict__ d4, bf16* __restrict__ d5,
    bf16* __restrict__ d6, int nbig, int nsmall)
{
    const int z = blockIdx.y;
    const float* s; bf16* d; int n;
    switch (z) {
        case 0: s = s0; d = d0; n = nbig;   break;
        case 1: s = s1; d = d1; n = nbig;   break;
        case 2: s = s2; d = d2; n = nbig;   break;
        case 3: s = s3; d = d3; n = nsmall; break;
        case 4: s = s4; d = d4; n = nsmall; break;
        case 5: s = s5; d = d5; n = nsmall; break;
        default: s = s6; d = d6; n = nsmall; break;
    }
    const int idx = (blockIdx.x * 256 + threadIdx.x) * 4;
    if (idx < n) {
        const float4 v = *reinterpret_cast<const float4*>(s + idx);
        union { ushort4 u; __bf16 h[4]; } r;
        r.h[0] = (__bf16)v.x; r.h[1] = (__bf16)v.y;
        r.h[2] = (__bf16)v.z; r.h[3] = (__bf16)v.w;
        *reinterpret_cast<ushort4*>(d + idx) = r.u;
    }
}

// ---------------------------------------------------------------------------
// GEMM: C[M,N] = A[M,K] @ W[N,K]^T + bias[N]; A,W bf16; bias f32; C per TC.
// m97 structure: BMx128 tile, BK=32, global_load_lds width-16 staging,
// 4 waves 2x2. BM=128: wave 64x64 via 4x4 of 16x16x32 (proven ~900 TF).
// BM=64: wave 32x64 via 2x4 -> twice the blocks, for grids that would
// otherwise be 1 block/CU (out-projection: 256 -> 512 blocks).
// ---------------------------------------------------------------------------
template <typename TC, bool VT3, int BM>
__global__ __launch_bounds__(256, BM == 128 ? 3 : 4) void gemm_bt_kernel(
    const bf16* __restrict__ A0, const bf16* __restrict__ A1, const bf16* __restrict__ A2,
    const bf16* __restrict__ W0, const bf16* __restrict__ W1, const bf16* __restrict__ W2,
    const float* __restrict__ b0, const float* __restrict__ b1, const float* __restrict__ b2,
    TC* __restrict__ C0, TC* __restrict__ C1, TC* __restrict__ C2,
    int M, int N, int K)
{
    const int z = blockIdx.z;
    const bf16*  A    = (z == 0) ? A0 : (z == 1) ? A1 : A2;
    const bf16*  W    = (z == 0) ? W0 : (z == 1) ? W1 : W2;
    const float* bias = (z == 0) ? b0 : (z == 1) ? b1 : b2;
    TC*          C    = (z == 0) ? C0 : (z == 1) ? C1 : C2;

    __shared__ bf16 As[BM][32];    // 64 B rows, NO pad (async-copy layout)
    __shared__ bf16 Bs[128][32];

    const int t    = threadIdx.x;
    const int lane = t & 63;
    const int wave = t >> 6;
    const int quad = lane >> 4;
    const int l16  = lane & 15;
    const int wm   = wave >> 1;
    const int wn   = wave & 1;

    const int m0 = blockIdx.y * BM;
    const int n0 = blockIdx.x * 128;

    constexpr int RPW = BM / 4;          // A rows staged per wave
    constexpr int MI  = BM / 32;         // 16-row fragments per wave in M
    const int ar0 = wave * RPW + (lane >> 2);
    const int br0 = wave * 32  + (lane >> 2);
    const int c0  = (lane & 3) * 8;
    const bf16* Ab = A + (size_t)(m0 + ar0) * K + c0;
    const bf16* Bb = W + (size_t)(n0 + br0) * K + c0;
    bf16* asd = &As[wave * RPW][0];
    bf16* bsd = &Bs[wave * 32][0];

    f32x4 acc[MI][4] = {};

    for (int kt = 0; kt < K; kt += 32) {
        __syncthreads();
        gll16(Ab + kt, asd);
        if constexpr (BM == 128) gll16(Ab + 16 * K + kt, asd + 16 * 32);
        gll16(Bb + kt, bsd);
        gll16(Bb + 16 * K + kt, bsd + 16 * 32);
        __syncthreads();

        bf16x8 af[MI], bfr[4];
#pragma unroll
        for (int mi = 0; mi < MI; mi++)
            af[mi] = *reinterpret_cast<const bf16x8*>(&As[wm * (BM / 2) + mi * 16 + l16][quad * 8]);
#pragma unroll
        for (int ni = 0; ni < 4; ni++)
            bfr[ni] = *reinterpret_cast<const bf16x8*>(&Bs[wn * 64 + ni * 16 + l16][quad * 8]);
#pragma unroll
        for (int mi = 0; mi < MI; mi++)
#pragma unroll
            for (int ni = 0; ni < 4; ni++)
                acc[mi][ni] = __builtin_amdgcn_mfma_f32_16x16x32_bf16(
                    af[mi], bfr[ni], acc[mi][ni], 0, 0, 0);
    }

    if (VT3 && z == 2) {
#pragma unroll
        for (int ni = 0; ni < 4; ni++) {
            const int col = n0 + wn * 64 + ni * 16 + l16;
            const float bvv = bias[col];
            const int hh = col >> 6, dh = col & 63;
#pragma unroll
            for (int mi = 0; mi < MI; mi++) {
                const int rb  = m0 + wm * (BM / 2) + mi * 16 + quad * 4;
                const int bb  = rb >> 11;
                const int tok = rb & (S_ - 1);
                union { ushort4 u; __bf16 h[4]; } pk;
#pragma unroll
                for (int i = 0; i < 4; i++)
                    pk.h[i] = (__bf16)(acc[mi][ni][i] + bvv);
                bf16* vt = (bf16*)C + ((size_t)(bb * H_ + hh) * DK_ + dh) * S_ + tok;
                *reinterpret_cast<ushort4*>(vt) = pk.u;
            }
        }
    } else {
#pragma unroll
        for (int ni = 0; ni < 4; ni++) {
            const int col = n0 + wn * 64 + ni * 16 + l16;
            const float bvv = bias[col];
#pragma unroll
            for (int mi = 0; mi < MI; mi++) {
#pragma unroll
                for (int i = 0; i < 4; i++) {
                    const int row = m0 + wm * (BM / 2) + mi * 16 + quad * 4 + i;
                    st1(&C[(size_t)row * N + col], acc[mi][ni][i] + bvv);
                }
            }
        }
    }
}

// ---------------------------------------------------------------------------
// Flash attention (causal), no-max exp2 softmax (validated R5-R7).
// This round: 128-row q-tiles, 8 waves (512 thr), PAIRED (TL=15-i, TS=i)
// -> every block runs exactly 34 chunk-intervals; grid (8,H,B) = 256 blocks,
// all co-resident (1/CU) -> 16 waves/CU (4/SIMD), 2x the latency-hiding TLP
// of the 64-row/4-wave version, and each staged 64-key chunk now feeds 8
// waves of compute (staging volume per unit compute halves).
// K and V^T chunks staged into LDS via global_load_lds DMA, double-buffered:
// chunk it+1's DMA issues AFTER the barrier and drains at the NEXT barrier
// -> in flight across all of chunk it's compute. Wave w owns rows
// [til*128+16w, +16): no split-K, no combine. Only diagonal-overlapping
// chunks mask; fully-masked chunks (k0 > qw0+15) are skipped wave-uniformly.
// XOR swizzle (cg ^= row&7) breaks the 128B-row-stride bank pathology.
// AO aliases Qp: each block reads only its own tiles' Q rows (TL at entry,
// TS at the switch) and writes only its own tiles' rows. Race-free.
// ---------------------------------------------------------------------------
__global__ __launch_bounds__(512, 4) void attn_kernel(
    const bf16* __restrict__ Qp, const bf16* __restrict__ Kp,
    const bf16* __restrict__ VT, bf16* __restrict__ AO)
{
    const int t    = threadIdx.x;
    const int lane = t & 63;
    const int wave = t >> 6;          // 0..7
    const int quad = lane >> 4;
    const int l16  = lane & 15;

    const int pairi  = blockIdx.x;    // 0..7
    const int TL     = 15 - pairi;    // long 128-row tile (8..15)
    const int TS     = pairi;         // short 128-row tile (0..7)
    const int h = blockIdx.y;
    const int b = blockIdx.z;
    const size_t bh = (size_t)b * S_ * D_ + (size_t)h * DK_;
    const bf16* vtb = VT + (size_t)(b * H_ + h) * DK_ * S_;

    __shared__ bf16 Ks[2][64][64];     // [buf][key][dk]   8 KB per buf
    __shared__ bf16 Vs[2][64][64];     // [buf][dh][key]   8 KB per buf
    __shared__ bf16 Pb[8][16][72];     // per-wave P tile (144 B rows)

    // staging lane constants: lane -> (row-within-8, swizzled col-group)
    const int sR  = lane >> 3;                // 0..7
    const int scg = ((lane & 7) ^ sR) * 8;    // element offset, XOR swizzle
    const int swz0 = (quad ^ (l16 & 7)) * 8;        // read swizzle, cols 0..31
    const int swz1 = ((quad + 4) ^ (l16 & 7)) * 8;  // read swizzle, cols 32..63

    const float QSC = 0.18033688f;   // 0.125 * log2(e)
    const float NEG = -1e30f;

    bf16x8 onesf;
#pragma unroll
    for (int j = 0; j < 8; j++) onesf[j] = (__bf16)1.0f;

    // Q fragments for this wave's 16 rows of the current tile
    int til = TL;
    bf16x8 qf0, qf1;
    {
        const bf16* qrow = Qp + bh + (size_t)(til * 128 + wave * 16 + l16) * D_;
        qf0 = *reinterpret_cast<const bf16x8*>(qrow + quad * 8);
        qf1 = *reinterpret_cast<const bf16x8*>(qrow + 32 + quad * 8);
#pragma unroll
        for (int j = 0; j < 8; j++) {
            qf0[j] = (__bf16)((float)qf0[j] * QSC);
            qf1[j] = (__bf16)((float)qf1[j] * QSC);
        }
    }

    f32x4 lacc = {};
    f32x4 oacc[4] = {};

    const int nA   = 2 * TL + 2;      // chunks for TL
    const int ntot = 34;              // nA + 2*TS+2 == 34 for every block

    // stage slot 0 (tile TL, keys 0..63) into buffer 0; 8 rows per wave
    {
        const int R = wave * 8 + sR;
        gll16(Kp + bh + (size_t)R * D_ + scg, &Ks[0][wave * 8][0]);
        gll16(vtb + (size_t)R * S_ + scg,     &Vs[0][wave * 8][0]);
    }

    int kcbase = 0;
    for (int it = 0; it < ntot; it++) {
        __syncthreads();   // drains DMA for slot `it`; prev-buf reads done

        // issue DMA for slot it+1 (drains at NEXT barrier -> true async)
        if (it + 1 < ntot) {
            const int itn  = it + 1;
            const int k0n  = ((itn < nA) ? itn : itn - nA) * 64;
            const int bufn = itn & 1;
            const int R = wave * 8 + sR;
            gll16(Kp + bh + (size_t)(k0n + R) * D_ + scg, &Ks[bufn][wave * 8][0]);
            gll16(vtb + (size_t)R * S_ + k0n + scg,       &Vs[bufn][wave * 8][0]);
        }

        // tile switch: flush TL output, load TS Q (wave-local)
        if (it == nA) {
            const int qw0 = til * 128 + wave * 16;
#pragma unroll
            for (int i = 0; i < 4; i++) {
                const float inv = 1.0f / lacc[i];
#pragma unroll
                for (int n = 0; n < 4; n++)
                    AO[bh + (size_t)(qw0 + quad * 4 + i) * D_ + n * 16 + l16] =
                        __float2bfloat16(oacc[n][i] * inv);
            }
            til = TS; kcbase = nA;
            const bf16* qrow = Qp + bh + (size_t)(til * 128 + wave * 16 + l16) * D_;
            qf0 = *reinterpret_cast<const bf16x8*>(qrow + quad * 8);
            qf1 = *reinterpret_cast<const bf16x8*>(qrow + 32 + quad * 8);
#pragma unroll
            for (int j = 0; j < 8; j++) {
                qf0[j] = (__bf16)((float)qf0[j] * QSC);
                qf1[j] = (__bf16)((float)qf1[j] * QSC);
            }
            lacc = f32x4{};
#pragma unroll
            for (int n = 0; n < 4; n++) oacc[n] = f32x4{};
        }

        const int kc  = it - kcbase;
        const int k0  = kc * 64;
        const int buf = it & 1;
        const int qw0 = til * 128 + wave * 16;

        // fully-masked chunk for this wave's 16 rows -> skip (wave-uniform)
        if (k0 > qw0 + 15) continue;

        // QK^T from staged K (swizzled b128 reads)
        f32x4 sc[4];
#pragma unroll
        for (int ch = 0; ch < 4; ch++) {
            const int row = ch * 16 + l16;
            bf16x8 kfa = *reinterpret_cast<const bf16x8*>(&Ks[buf][row][swz0]);
            bf16x8 kfb = *reinterpret_cast<const bf16x8*>(&Ks[buf][row][swz1]);
            f32x4 zz = {};
            zz = __builtin_amdgcn_mfma_f32_16x16x32_bf16(qf0, kfa, zz, 0, 0, 0);
            sc[ch] = __builtin_amdgcn_mfma_f32_16x16x32_bf16(qf1, kfb, zz, 0, 0, 0);
        }

        // exp2 softmax (no max-sub); mask only diagonal-overlapping chunks
        const bool bnd = (k0 + 63 > qw0);
#pragma unroll
        for (int i = 0; i < 4; i++) {
            const int r = quad * 4 + i;
            float s0 = sc[0][i], s1 = sc[1][i], s2 = sc[2][i], s3 = sc[3][i];
            if (bnd) {
                const int qi = qw0 + r;
                s0 = (k0 + l16      <= qi) ? s0 : NEG;
                s1 = (k0 + 16 + l16 <= qi) ? s1 : NEG;
                s2 = (k0 + 32 + l16 <= qi) ? s2 : NEG;
                s3 = (k0 + 48 + l16 <= qi) ? s3 : NEG;
            }
            Pb[wave][r][l16]      = __float2bfloat16(__builtin_amdgcn_exp2f(s0));
            Pb[wave][r][16 + l16] = __float2bfloat16(__builtin_amdgcn_exp2f(s1));
            Pb[wave][r][32 + l16] = __float2bfloat16(__builtin_amdgcn_exp2f(s2));
            Pb[wave][r][48 + l16] = __float2bfloat16(__builtin_amdgcn_exp2f(s3));
        }
        // wave-private LDS round-trip: drain ds_writes before reads
        asm volatile("s_waitcnt lgkmcnt(0)" ::: "memory");
        bf16x8 pf0 = *reinterpret_cast<const bf16x8*>(&Pb[wave][l16][quad * 8]);
        bf16x8 pf1 = *reinterpret_cast<const bf16x8*>(&Pb[wave][l16][32 + quad * 8]);

        lacc = __builtin_amdgcn_mfma_f32_16x16x32_bf16(pf0, onesf, lacc, 0, 0, 0);
        lacc = __builtin_amdgcn_mfma_f32_16x16x32_bf16(pf1, onesf, lacc, 0, 0, 0);

        // PV from staged V^T (swizzled b128 reads)
#pragma unroll
        for (int n = 0; n < 4; n++) {
            const int row = n * 16 + l16;
            bf16x8 vt0 = *reinterpret_cast<const bf16x8*>(&Vs[buf][row][swz0]);
            bf16x8 vt1 = *reinterpret_cast<const bf16x8*>(&Vs[buf][row][swz1]);
            oacc[n] = __builtin_amdgcn_mfma_f32_16x16x32_bf16(pf0, vt0, oacc[n], 0, 0, 0);
            oacc[n] = __builtin_amdgcn_mfma_f32_16x16x32_bf16(pf1, vt1, oacc[n], 0, 0, 0);
        }
    }

    // epilogue for the second tile (TS)
    {
        const int qw0 = til * 128 + wave * 16;
#pragma unroll
        for (int i = 0; i < 4; i++) {
            const float inv = 1.0f / lacc[i];
#pragma unroll
            for (int n = 0; n < 4; n++)
                AO[bh + (size_t)(qw0 + quad * 4 + i) * D_ + n * 16 + l16] =
                    __float2bfloat16(oacc[n][i] * inv);
        }
    }
}

// ---------------------------------------------------------------------------
extern "C" void kernel_launch(void* const* d_in, const int* in_sizes, int n_in,
                              void* d_out, int out_size, void* d_ws, size_t ws_size,
                              hipStream_t stream)
{
    const float* q  = (const float*)d_in[0];
    const float* k  = (const float*)d_in[1];
    const float* v  = (const float*)d_in[2];
    // d_in[3]: causal mask (int32 tril) — applied analytically
    const float* Wq = (const float*)d_in[4];
    const float* bq = (const float*)d_in[5];
    const float* Wk = (const float*)d_in[6];
    const float* bk = (const float*)d_in[7];
    const float* Wv = (const float*)d_in[8];
    const float* bv = (const float*)d_in[9];
    const float* Wo = (const float*)d_in[10];
    const float* bo = (const float*)d_in[11];
    float* out = (float*)d_out;

    bf16* ws = (bf16*)d_ws;
    const size_t MD = (size_t)(B_ * S_) * D_;   // 4,194,304
    const size_t WN = (size_t)D_ * D_;          // 1,048,576
    bf16* qb  = ws;
    bf16* kb  = ws + MD;
    bf16* vb  = ws + 2 * MD;
    bf16* wqb = ws + 3 * MD;
    bf16* wkb = wqb + WN;
    bf16* wvb = wkb + WN;
    bf16* wob = wvb + WN;
    bf16* Qp  = wob + WN;
    bf16* Kp  = Qp + MD;
    bf16* VT  = Kp + MD;    // total 6*MD + 4*WN ~= 58.7 MB
    bf16* AO  = Qp;         // alias: safe (see attn_kernel note)

    const int M = B_ * S_;  // 4096

    // 1) convert all f32 operands to bf16 (one launch, 7 regions)
    cvt_kernel<<<dim3((int)(MD / 4 / 256), 7), 256, 0, stream>>>(
        q, k, v, Wq, Wk, Wv, Wo, qb, kb, vb, wqb, wkb, wvb, wob,
        (int)MD, (int)WN);

    // 2) QKV projections (z batched); z==2 writes V^T per head
    gemm_bt_kernel<bf16, true, 128><<<dim3(D_ / 128, M / 128, 3), 256, 0, stream>>>(
        qb, kb, vb, wqb, wkb, wvb, bq, bk, bv, Qp, Kp, VT, M, D_, D_);

    // 3) causal flash attention (128-row paired tiles, 8 waves, 256 blocks)
    attn_kernel<<<dim3(8, H_, B_), 512, 0, stream>>>(Qp, Kp, VT, AO);

    // 4) output projection -> f32 out (BM=64: 512 blocks vs 256)
    gemm_bt_kernel<float, false, 64><<<dim3(D_ / 128, M / 64, 1), 256, 0, stream>>>(
        AO, AO, AO, wob, wob, wob, bo, bo, bo, out, out, out, M, D_, D_);
}

// Round 3
// 228.534 us; speedup vs baseline: 1.1302x; 1.0396x over previous
//
#include <hip/hip_runtime.h>
#include <hip/hip_bf16.h>

// Problem constants (from reference): B=2, S=2048, D=1024, H=16, DK=64
#define B_  2
#define S_  2048
#define D_  1024
#define H_  16
#define DK_ 64

using bf16 = __hip_bfloat16;
typedef __bf16 bf16x8 __attribute__((ext_vector_type(8)));
typedef float  f32x4  __attribute__((ext_vector_type(4)));

__device__ inline void st1(float* p, float v) { *p = v; }
__device__ inline void st1(bf16*  p, float v) { *p = __float2bfloat16(v); }

// Async global->LDS, 16B per lane. LDS dest = wave-uniform base + lane*16.
__device__ inline void gll16(const bf16* g, bf16* l) {
    __builtin_amdgcn_global_load_lds(
        (const __attribute__((address_space(1))) unsigned int*)g,
        (__attribute__((address_space(3))) unsigned int*)l, 16, 0, 0);
}

// ---------------------------------------------------------------------------
// f32 -> bf16 conversion: 7 regions (q,k,v = nbig; Wq,Wk,Wv,Wo = nsmall).
// ---------------------------------------------------------------------------
__global__ __launch_bounds__(256) void cvt_kernel(
    const float* __restrict__ s0, const float* __restrict__ s1,
    const float* __restrict__ s2, const float* __restrict__ s3,
    const float* __restrict__ s4, const float* __restrict__ s5,
    const float* __restrict__ s6,
    bf16* __restrict__ d0, bf16* __restrict__ d1, bf16* __restrict__ d2,
    bf16* __restrict__ d3, bf16* __restrict__ d4, bf16* __restrict__ d5,
    bf16* __restrict__ d6, int nbig, int nsmall)
{
    const int z = blockIdx.y;
    const float* s; bf16* d; int n;
    switch (z) {
        case 0: s = s0; d = d0; n = nbig;   break;
        case 1: s = s1; d = d1; n = nbig;   break;
        case 2: s = s2; d = d2; n = nbig;   break;
        case 3: s = s3; d = d3; n = nsmall; break;
        case 4: s = s4; d = d4; n = nsmall; break;
        case 5: s = s5; d = d5; n = nsmall; break;
        default: s = s6; d = d6; n = nsmall; break;
    }
    const int idx = (blockIdx.x * 256 + threadIdx.x) * 4;
    if (idx < n) {
        const float4 v = *reinterpret_cast<const float4*>(s + idx);
        union { ushort4 u; __bf16 h[4]; } r;
        r.h[0] = (__bf16)v.x; r.h[1] = (__bf16)v.y;
        r.h[2] = (__bf16)v.z; r.h[3] = (__bf16)v.w;
        *reinterpret_cast<ushort4*>(d + idx) = r.u;
    }
}

// ---------------------------------------------------------------------------
// GEMM: C[M,N] = A[M,K] @ W[N,K]^T + bias[N]; A,W bf16; bias f32; C per TC.
// m97 structure: BMx128 tile, BK=32, global_load_lds width-16 staging,
// 4 waves 2x2. BM=128: wave 64x64 via 4x4 of 16x16x32 (proven ~900 TF).
// BM=64: wave 32x64 via 2x4 -> twice the blocks, for grids that would
// otherwise be 1 block/CU (out-projection: 256 -> 512 blocks).
// ---------------------------------------------------------------------------
template <typename TC, bool VT3, int BM>
__global__ __launch_bounds__(256, BM == 128 ? 3 : 4) void gemm_bt_kernel(
    const bf16* __restrict__ A0, const bf16* __restrict__ A1, const bf16* __restrict__ A2,
    const bf16* __restrict__ W0, const bf16* __restrict__ W1, const bf16* __restrict__ W2,
    const float* __restrict__ b0, const float* __restrict__ b1, const float* __restrict__ b2,
    TC* __restrict__ C0, TC* __restrict__ C1, TC* __restrict__ C2,
    int M, int N, int K)
{
    const int z = blockIdx.z;
    const bf16*  A    = (z == 0) ? A0 : (z == 1) ? A1 : A2;
    const bf16*  W    = (z == 0) ? W0 : (z == 1) ? W1 : W2;
    const float* bias = (z == 0) ? b0 : (z == 1) ? b1 : b2;
    TC*          C    = (z == 0) ? C0 : (z == 1) ? C1 : C2;

    __shared__ bf16 As[BM][32];    // 64 B rows, NO pad (async-copy layout)
    __shared__ bf16 Bs[128][32];

    const int t    = threadIdx.x;
    const int lane = t & 63;
    const int wave = t >> 6;
    const int quad = lane >> 4;
    const int l16  = lane & 15;
    const int wm   = wave >> 1;
    const int wn   = wave & 1;

    const int m0 = blockIdx.y * BM;
    const int n0 = blockIdx.x * 128;

    constexpr int RPW = BM / 4;          // A rows staged per wave
    constexpr int MI  = BM / 32;         // 16-row fragments per wave in M
    const int ar0 = wave * RPW + (lane >> 2);
    const int br0 = wave * 32  + (lane >> 2);
    const int c0  = (lane & 3) * 8;
    const bf16* Ab = A + (size_t)(m0 + ar0) * K + c0;
    const bf16* Bb = W + (size_t)(n0 + br0) * K + c0;
    bf16* asd = &As[wave * RPW][0];
    bf16* bsd = &Bs[wave * 32][0];

    f32x4 acc[MI][4] = {};

    for (int kt = 0; kt < K; kt += 32) {
        __syncthreads();
        gll16(Ab + kt, asd);
        if constexpr (BM == 128) gll16(Ab + 16 * K + kt, asd + 16 * 32);
        gll16(Bb + kt, bsd);
        gll16(Bb + 16 * K + kt, bsd + 16 * 32);
        __syncthreads();

        bf16x8 af[MI], bfr[4];
#pragma unroll
        for (int mi = 0; mi < MI; mi++)
            af[mi] = *reinterpret_cast<const bf16x8*>(&As[wm * (BM / 2) + mi * 16 + l16][quad * 8]);
#pragma unroll
        for (int ni = 0; ni < 4; ni++)
            bfr[ni] = *reinterpret_cast<const bf16x8*>(&Bs[wn * 64 + ni * 16 + l16][quad * 8]);
#pragma unroll
        for (int mi = 0; mi < MI; mi++)
#pragma unroll
            for (int ni = 0; ni < 4; ni++)
                acc[mi][ni] = __builtin_amdgcn_mfma_f32_16x16x32_bf16(
                    af[mi], bfr[ni], acc[mi][ni], 0, 0, 0);
    }

    if (VT3 && z == 2) {
#pragma unroll
        for (int ni = 0; ni < 4; ni++) {
            const int col = n0 + wn * 64 + ni * 16 + l16;
            const float bvv = bias[col];
            const int hh = col >> 6, dh = col & 63;
#pragma unroll
            for (int mi = 0; mi < MI; mi++) {
                const int rb  = m0 + wm * (BM / 2) + mi * 16 + quad * 4;
                const int bb  = rb >> 11;
                const int tok = rb & (S_ - 1);
                union { ushort4 u; __bf16 h[4]; } pk;
#pragma unroll
                for (int i = 0; i < 4; i++)
                    pk.h[i] = (__bf16)(acc[mi][ni][i] + bvv);
                bf16* vt = (bf16*)C + ((size_t)(bb * H_ + hh) * DK_ + dh) * S_ + tok;
                *reinterpret_cast<ushort4*>(vt) = pk.u;
            }
        }
    } else {
#pragma unroll
        for (int ni = 0; ni < 4; ni++) {
            const int col = n0 + wn * 64 + ni * 16 + l16;
            const float bvv = bias[col];
#pragma unroll
            for (int mi = 0; mi < MI; mi++) {
#pragma unroll
                for (int i = 0; i < 4; i++) {
                    const int row = m0 + wm * (BM / 2) + mi * 16 + quad * 4 + i;
                    st1(&C[(size_t)row * N + col], acc[mi][ni][i] + bvv);
                }
            }
        }
    }
}

// ---------------------------------------------------------------------------
// Flash attention (causal), no-max exp2 softmax (validated R5-R7).
// Structure: paired 64-row q-tiles (tLong=31-i, tShort=i), 4 waves, 512
// blocks (2/CU) -- the best-measured R0 geometry -- with a NEW sync skeleton:
//   * TRIPLE-buffered K/V chunks,
//   * raw s_barrier (no vmcnt(0) drain),
//   * counted s_waitcnt vmcnt(4): chunk it+1's 4 DMA ops are issued before
//     the barrier and stay IN FLIGHT across it, draining only at the NEXT
//     interval's vmcnt(4). DMA latency leaves the per-interval critical path
//     (T3/T4 counted-vmcnt pattern; the vmcnt(0)-before-barrier drain was
//     the fixed ~3.5k-cycle interval cost measured in R0/R2).
// Race argument (1 barrier/interval, 3 buffers): interval `it` reads buf
// it%3; DMA issued at `it` writes buf (it+1)%3; buf (it+2)%3 == (it-1)%3 is
// idle. A wave issues DMA into (it+1)%3 only after passing barrier it, which
// every wave reaches only after finishing reads of (it-1)%3 (= the buffer's
// previous tenant) at interval it-1. Per-wave vmcnt(4) before barrier `it+1`
// proves that wave's chunk-it loads landed; the barrier publishes it.
// Q for BOTH tiles preloaded at prologue (register copy at the switch; no
// compiler-forced vmcnt(0) drain mid-loop).
// XOR swizzle (cg ^= row&7) breaks the 128B-row-stride bank pathology.
// AO aliases Qp: both tiles' Q are read at the prologue, before ANY block
// can flush rows of this (tile,head); tiles are disjoint across blocks.
// ---------------------------------------------------------------------------
__global__ __launch_bounds__(256, 2) void attn_kernel(
    const bf16* __restrict__ Qp, const bf16* __restrict__ Kp,
    const bf16* __restrict__ VT, bf16* __restrict__ AO)
{
    const int t    = threadIdx.x;
    const int lane = t & 63;
    const int wave = t >> 6;
    const int quad = lane >> 4;
    const int l16  = lane & 15;

    const int pairi  = blockIdx.x;        // 0..15
    const int tLong  = 31 - pairi;        // tiles 31..16 (processed first)
    const int tShort = pairi;             // tiles 0..15
    const int h = blockIdx.y;
    const int b = blockIdx.z;
    const size_t bh = (size_t)b * S_ * D_ + (size_t)h * DK_;
    const bf16* vtb = VT + (size_t)(b * H_ + h) * DK_ * S_;

    __shared__ bf16 Ks[3][64][64];     // [buf][key][dk]   8 KB per buf
    __shared__ bf16 Vs[3][64][64];     // [buf][dh][key]   8 KB per buf
    __shared__ bf16 Pb[4][16][72];     // per-wave P tile (144 B rows)

    // staging lane constants: lane -> (row-within-8, swizzled col-group)
    const int sR = lane >> 3;                 // 0..7
    const int scg = ((lane & 7) ^ sR) * 8;    // element offset, XOR swizzle
    const int swz0 = (quad ^ (l16 & 7)) * 8;        // read swizzle, cols 0..31
    const int swz1 = ((quad + 4) ^ (l16 & 7)) * 8;  // read swizzle, cols 32..63

    const float QSC = 0.18033688f;   // 0.125 * log2(e)
    const float NEG = -1e30f;

    bf16x8 onesf;
#pragma unroll
    for (int j = 0; j < 8; j++) onesf[j] = (__bf16)1.0f;

    // Preload Q fragments for BOTH tiles (switch = register copy)
    bf16x8 qA0, qA1, qB0, qB1;
    {
        const bf16* qrow = Qp + bh + (size_t)(tLong * 64 + wave * 16 + l16) * D_;
        qA0 = *reinterpret_cast<const bf16x8*>(qrow + quad * 8);
        qA1 = *reinterpret_cast<const bf16x8*>(qrow + 32 + quad * 8);
        const bf16* qrs = Qp + bh + (size_t)(tShort * 64 + wave * 16 + l16) * D_;
        qB0 = *reinterpret_cast<const bf16x8*>(qrs + quad * 8);
        qB1 = *reinterpret_cast<const bf16x8*>(qrs + 32 + quad * 8);
#pragma unroll
        for (int j = 0; j < 8; j++) {
            qA0[j] = (__bf16)((float)qA0[j] * QSC);
            qA1[j] = (__bf16)((float)qA1[j] * QSC);
            qB0[j] = (__bf16)((float)qB0[j] * QSC);
            qB1[j] = (__bf16)((float)qB1[j] * QSC);
        }
    }

    int til = tLong;
    bf16x8 qf0 = qA0, qf1 = qA1;

    f32x4 lacc = {};
    f32x4 oacc[4] = {};

    const int nA   = tLong + 1;
    const int ntot = 33;              // nA + tShort+1 == 33 for every block

    // prologue: stage chunk 0 (tile tLong, keys 0..63) into buffer 0
    {
#pragma unroll
        for (int j = 0; j < 2; j++) {
            const int R = wave * 16 + j * 8 + sR;
            gll16(Kp + bh + (size_t)R * D_ + scg, &Ks[0][wave * 16 + j * 8][0]);
            gll16(vtb + (size_t)R * S_ + scg,     &Vs[0][wave * 16 + j * 8][0]);
        }
    }

    int cur = 0, kcbase = 0;
    for (int it = 0; it < ntot; it++) {
        const int nxt = (cur == 2) ? 0 : cur + 1;

        // issue DMA for chunk it+1 into buf `nxt`; wait ONLY chunk it's 4
        // loads (vmcnt(4) leaves the new 4 in flight across the barrier)
        if (it + 1 < ntot) {
            const int itn = it + 1;
            const int k0n = ((itn < nA) ? itn : itn - nA) * 64;
#pragma unroll
            for (int j = 0; j < 2; j++) {
                const int R = wave * 16 + j * 8 + sR;
                gll16(Kp + bh + (size_t)(k0n + R) * D_ + scg, &Ks[nxt][wave * 16 + j * 8][0]);
                gll16(vtb + (size_t)R * S_ + k0n + scg,       &Vs[nxt][wave * 16 + j * 8][0]);
            }
            asm volatile("s_waitcnt vmcnt(4)" ::: "memory");
        } else {
            asm volatile("s_waitcnt vmcnt(0)" ::: "memory");
        }
        __builtin_amdgcn_s_barrier();
        asm volatile("" ::: "memory");

        // tile switch: flush tLong output, swap to preloaded tShort Q
        if (it == nA) {
            const int qw0 = til * 64 + wave * 16;
#pragma unroll
            for (int i = 0; i < 4; i++) {
                const float inv = 1.0f / lacc[i];
#pragma unroll
                for (int n = 0; n < 4; n++)
                    AO[bh + (size_t)(qw0 + quad * 4 + i) * D_ + n * 16 + l16] =
                        __float2bfloat16(oacc[n][i] * inv);
            }
            til = tShort; kcbase = nA;
            qf0 = qB0; qf1 = qB1;
            lacc = f32x4{};
#pragma unroll
            for (int n = 0; n < 4; n++) oacc[n] = f32x4{};
        }

        const int kc  = it - kcbase;
        const int k0  = kc * 64;
        const int qw0 = til * 64 + wave * 16;

        // QK^T from staged K (swizzled b128 reads)
        f32x4 sc[4];
#pragma unroll
        for (int ch = 0; ch < 4; ch++) {
            const int row = ch * 16 + l16;
            bf16x8 kfa = *reinterpret_cast<const bf16x8*>(&Ks[cur][row][swz0]);
            bf16x8 kfb = *reinterpret_cast<const bf16x8*>(&Ks[cur][row][swz1]);
            f32x4 zz = {};
            zz = __builtin_amdgcn_mfma_f32_16x16x32_bf16(qf0, kfa, zz, 0, 0, 0);
            sc[ch] = __builtin_amdgcn_mfma_f32_16x16x32_bf16(qf1, kfb, zz, 0, 0, 0);
        }

        // exp2 softmax (no max-sub); mask only the diagonal chunk
        const bool bnd = (kc == til);
#pragma unroll
        for (int i = 0; i < 4; i++) {
            const int r = quad * 4 + i;
            float s0 = sc[0][i], s1 = sc[1][i], s2 = sc[2][i], s3 = sc[3][i];
            if (bnd) {
                const int qi = qw0 + r;
                s0 = (k0 + l16      <= qi) ? s0 : NEG;
                s1 = (k0 + 16 + l16 <= qi) ? s1 : NEG;
                s2 = (k0 + 32 + l16 <= qi) ? s2 : NEG;
                s3 = (k0 + 48 + l16 <= qi) ? s3 : NEG;
            }
            Pb[wave][r][l16]      = __float2bfloat16(__builtin_amdgcn_exp2f(s0));
            Pb[wave][r][16 + l16] = __float2bfloat16(__builtin_amdgcn_exp2f(s1));
            Pb[wave][r][32 + l16] = __float2bfloat16(__builtin_amdgcn_exp2f(s2));
            Pb[wave][r][48 + l16] = __float2bfloat16(__builtin_amdgcn_exp2f(s3));
        }
        // wave-private LDS round-trip: drain ds_writes before reads
        asm volatile("s_waitcnt lgkmcnt(0)" ::: "memory");
        bf16x8 pf0 = *reinterpret_cast<const bf16x8*>(&Pb[wave][l16][quad * 8]);
        bf16x8 pf1 = *reinterpret_cast<const bf16x8*>(&Pb[wave][l16][32 + quad * 8]);

        lacc = __builtin_amdgcn_mfma_f32_16x16x32_bf16(pf0, onesf, lacc, 0, 0, 0);
        lacc = __builtin_amdgcn_mfma_f32_16x16x32_bf16(pf1, onesf, lacc, 0, 0, 0);

        // PV from staged V^T (swizzled b128 reads)
#pragma unroll
        for (int n = 0; n < 4; n++) {
            const int row = n * 16 + l16;
            bf16x8 vt0 = *reinterpret_cast<const bf16x8*>(&Vs[cur][row][swz0]);
            bf16x8 vt1 = *reinterpret_cast<const bf16x8*>(&Vs[cur][row][swz1]);
            oacc[n] = __builtin_amdgcn_mfma_f32_16x16x32_bf16(pf0, vt0, oacc[n], 0, 0, 0);
            oacc[n] = __builtin_amdgcn_mfma_f32_16x16x32_bf16(pf1, vt1, oacc[n], 0, 0, 0);
        }

        cur = nxt;
    }

    // epilogue for the second tile
    {
        const int qw0 = til * 64 + wave * 16;
#pragma unroll
        for (int i = 0; i < 4; i++) {
            const float inv = 1.0f / lacc[i];
#pragma unroll
            for (int n = 0; n < 4; n++)
                AO[bh + (size_t)(qw0 + quad * 4 + i) * D_ + n * 16 + l16] =
                    __float2bfloat16(oacc[n][i] * inv);
        }
    }
}

// ---------------------------------------------------------------------------
extern "C" void kernel_launch(void* const* d_in, const int* in_sizes, int n_in,
                              void* d_out, int out_size, void* d_ws, size_t ws_size,
                              hipStream_t stream)
{
    const float* q  = (const float*)d_in[0];
    const float* k  = (const float*)d_in[1];
    const float* v  = (const float*)d_in[2];
    // d_in[3]: causal mask (int32 tril) — applied analytically
    const float* Wq = (const float*)d_in[4];
    const float* bq = (const float*)d_in[5];
    const float* Wk = (const float*)d_in[6];
    const float* bk = (const float*)d_in[7];
    const float* Wv = (const float*)d_in[8];
    const float* bv = (const float*)d_in[9];
    const float* Wo = (const float*)d_in[10];
    const float* bo = (const float*)d_in[11];
    float* out = (float*)d_out;

    bf16* ws = (bf16*)d_ws;
    const size_t MD = (size_t)(B_ * S_) * D_;   // 4,194,304
    const size_t WN = (size_t)D_ * D_;          // 1,048,576
    bf16* qb  = ws;
    bf16* kb  = ws + MD;
    bf16* vb  = ws + 2 * MD;
    bf16* wqb = ws + 3 * MD;
    bf16* wkb = wqb + WN;
    bf16* wvb = wkb + WN;
    bf16* wob = wvb + WN;
    bf16* Qp  = wob + WN;
    bf16* Kp  = Qp + MD;
    bf16* VT  = Kp + MD;    // total 6*MD + 4*WN ~= 58.7 MB
    bf16* AO  = Qp;         // alias: safe (see attn_kernel note)

    const int M = B_ * S_;  // 4096

    // 1) convert all f32 operands to bf16 (one launch, 7 regions)
    cvt_kernel<<<dim3((int)(MD / 4 / 256), 7), 256, 0, stream>>>(
        q, k, v, Wq, Wk, Wv, Wo, qb, kb, vb, wqb, wkb, wvb, wob,
        (int)MD, (int)WN);

    // 2) QKV projections (z batched); z==2 writes V^T per head
    gemm_bt_kernel<bf16, true, 128><<<dim3(D_ / 128, M / 128, 3), 256, 0, stream>>>(
        qb, kb, vb, wqb, wkb, wvb, bq, bk, bv, Qp, Kp, VT, M, D_, D_);

    // 3) causal flash attention (paired 64-row tiles, triple-buffered DMA,
    //    counted vmcnt -- loads in flight across barriers)
    attn_kernel<<<dim3(16, H_, B_), 256, 0, stream>>>(Qp, Kp, VT, AO);

    // 4) output projection -> f32 out (BM=64: 512 blocks)
    gemm_bt_kernel<float, false, 64><<<dim3(D_ / 128, M / 64, 1), 256, 0, stream>>>(
        AO, AO, AO, wob, wob, wob, bo, bo, bo, out, out, out, M, D_, D_);
}